// Round 7
// baseline (502.183 us; speedup 1.0000x reference)
//
#include <hip/hip_runtime.h>
#include <stdint.h>

typedef __attribute__((ext_vector_type(4))) float f32x4;
typedef __attribute__((ext_vector_type(16))) float f32x16;
typedef __attribute__((ext_vector_type(8))) short bf16x8;
typedef unsigned short u16;

#define MFMA(a, b, c) __builtin_amdgcn_mfma_f32_16x16x32_bf16(a, b, c, 0, 0, 0)
#define MFMA32(a, b, c) __builtin_amdgcn_mfma_f32_32x32x16_bf16(a, b, c, 0, 0, 0)
#define EXP2(x) __builtin_amdgcn_exp2f(x)

__device__ __forceinline__ u16 f2bf(float f) {
  union { float f; unsigned u; } x; x.f = f;
  unsigned r = x.u + 0x7fffu + ((x.u >> 16) & 1u);
  return (u16)(r >> 16);
}

__device__ __forceinline__ unsigned cvtpk(float lo, float hi) {
  unsigned r;
  asm("v_cvt_pk_bf16_f32 %0, %1, %2" : "=v"(r) : "v"(lo), "v"(hi));
  return r;
}

// swap: a[32..63] <-> b[0..31]
__device__ __forceinline__ void pl32swap(unsigned& a, unsigned& b) {
  asm volatile("v_permlane32_swap_b32 %0, %1" : "+v"(a), "+v"(b));
}

__device__ __forceinline__ void gload16(const void* g, void* l) {
  __builtin_amdgcn_global_load_lds(
      (const __attribute__((address_space(1))) unsigned int*)g,
      (__attribute__((address_space(3))) unsigned int*)l, 16, 0, 0);
}

// ---------------------------------------------------------------- cast f32->bf16
__global__ void __launch_bounds__(256) cast_bf16(const float* __restrict__ in,
                                                 u16* __restrict__ out, int n4) {
  int i = blockIdx.x * 256 + threadIdx.x;
  if (i >= n4) return;
  float4 v = reinterpret_cast<const float4*>(in)[i];
  ushort4 o;
  o.x = f2bf(v.x); o.y = f2bf(v.y); o.z = f2bf(v.z); o.w = f2bf(v.w);
  reinterpret_cast<ushort4*>(out)[i] = o;
}

// ---------------------------------------------------------------- GEMM C = A * B^T
template <int EPI>
__global__ void __launch_bounds__(256, 2)
gemm_bt(const u16* __restrict__ A, const u16* __restrict__ B,
        void* __restrict__ C0, void* __restrict__ C1, void* __restrict__ C2,
        int M, int N, int K, int MB) {
  __shared__ alignas(16) u16 sm[8192];  // A tile [128][32] @0, B tile [128][32] @4096
  const int tid = threadIdx.x;
  const int w = tid >> 6, lane = tid & 63;
  const int lr = lane & 15, g = lane >> 4;
  const int mb = blockIdx.x % MB, nb = blockIdx.x / MB;
  const int m0 = mb * 128, n0 = nb * 128;

  const u16* src[4];
  u16* dst[4];
#pragma unroll
  for (int i = 0; i < 4; ++i) {
    int c = w * 4 + i;
    int r = (c & 7) * 16 + (lane >> 2);
    int sb = (lane & 3) ^ ((r >> 1) & 3);
    src[i] = (c < 8) ? (A + (size_t)(m0 + r) * K + sb * 8)
                     : (B + (size_t)(n0 + r) * K + sb * 8);
    dst[i] = &sm[c * 512];
  }

  f32x4 acc[4][4];
#pragma unroll
  for (int x = 0; x < 4; ++x)
#pragma unroll
    for (int y = 0; y < 4; ++y) acc[x][y] = f32x4{0.f, 0.f, 0.f, 0.f};

  const int rowb = (w >> 1) * 64, colb = (w & 1) * 64;
  const int nk = K >> 5;
  for (int kt = 0; kt < nk; ++kt) {
#pragma unroll
    for (int i = 0; i < 4; ++i) gload16(src[i] + kt * 32, dst[i]);
    __syncthreads();
    bf16x8 af[4], bfr[4];
#pragma unroll
    for (int mi = 0; mi < 4; ++mi) {
      int r = rowb + mi * 16 + lr;
      af[mi] = *(const bf16x8*)((const char*)sm + r * 64 +
                                ((g * 16) ^ (((r >> 1) & 3) << 4)));
    }
#pragma unroll
    for (int ni = 0; ni < 4; ++ni) {
      int r = colb + ni * 16 + lr;
      bfr[ni] = *(const bf16x8*)((const char*)sm + 8192 + r * 64 +
                                 ((g * 16) ^ (((r >> 1) & 3) << 4)));
    }
#pragma unroll
    for (int mi = 0; mi < 4; ++mi)
#pragma unroll
      for (int ni = 0; ni < 4; ++ni)
        acc[mi][ni] = MFMA(af[mi], bfr[ni], acc[mi][ni]);
    __syncthreads();
  }

  if (EPI == 0) {
    u16* qo = (u16*)C0;
    u16* ko = (u16*)C1;
    u16* vo = (u16*)C2;
#pragma unroll
    for (int mi = 0; mi < 4; ++mi) {
      int s0 = m0 + rowb + mi * 16 + g * 4;
#pragma unroll
      for (int ni = 0; ni < 4; ++ni) {
        int n = n0 + colb + ni * 16 + lr;
        int t = n >> 11, hh = (n >> 7) & 15, d = n & 127;
        if (t == 2) {  // v transposed: [NH][HD][S], 4 consecutive s per lane
          ushort4 pk;
          pk.x = f2bf(acc[mi][ni][0]);
          pk.y = f2bf(acc[mi][ni][1]);
          pk.z = f2bf(acc[mi][ni][2]);
          pk.w = f2bf(acc[mi][ni][3]);
          *(ushort4*)(vo + (size_t)(hh * 128 + d) * 4096 + s0) = pk;
        } else {
          u16* dq = (t == 0 ? qo : ko) + (size_t)(hh * 4096 + s0) * 128 + d;
#pragma unroll
          for (int j = 0; j < 4; ++j) dq[(size_t)j * 128] = f2bf(acc[mi][ni][j]);
        }
      }
    }
  } else {
    float* C = (float*)C0;
#pragma unroll
    for (int mi = 0; mi < 4; ++mi)
#pragma unroll
      for (int ni = 0; ni < 4; ++ni) {
        size_t r0 = (size_t)(m0 + rowb + mi * 16 + g * 4);
        int cn = n0 + colb + ni * 16 + lr;
#pragma unroll
        for (int j = 0; j < 4; ++j) C[(r0 + j) * N + cn] = acc[mi][ni][j];
      }
  }
}

// ---------------------------------------------------------------- flash attention
// In-block split-KV: 8 waves (512 thr). Waves 0-3: kv[0,2048), waves 4-7: kv[2048,4096),
// both over the SAME 256 q rows (wave w&3 owns 64 q). 32x32x16 MFMA, in-register P,
// O^T accumulate; per-group K/V double-buffered in LDS (4 tiles x 2 bufs = 128 KB).
// End: waves 4-7 dump (O',m,l) to LDS; waves 0-3 merge (exact split-softmax) and store.
// Grid 256 = 1 block/CU (8 waves = 2/SIMD). XCD-swizzled for K/V L2 residency.
__global__ void __launch_bounds__(512, 2)
attn_kernel(const u16* __restrict__ qg, const u16* __restrict__ kg,
            const u16* __restrict__ vtg, u16* __restrict__ og) {
  __shared__ alignas(16) char smb[135168];  // 128 KB staging; 132 KB combine (reused)
  const int tid = threadIdx.x;
  const int w = tid >> 6, lane = tid & 63;
  const int ql = lane & 31, hl = lane >> 5;
  const int bsw = (blockIdx.x & 7) * 32 + (blockIdx.x >> 3);  // XCD swizzle (256=8*32)
  const int h = bsw >> 4;
  const int qb = bsw & 15;
  const int g2 = w >> 2;   // compute kv-group
  const int qw = w & 3;    // q sub-block within group

  // staging roles: w0,1 K-g0 | w2,3 V-g0 | w4,5 K-g1 | w6,7 V-g1 (8 chunks each)
  const u16* ssrc[8];
  unsigned sdst[8];  // byte offsets into smb (buffer 0); buffer 1 = +16384
  size_t sstep;
  {
    const int sg = w >> 2;
    if (!(w & 2)) {  // K stager: tile [64][128] u16, 16 chunks of 1KB
      sstep = 64 * 128;
#pragma unroll
      for (int i = 0; i < 8; ++i) {
        int c = (w & 1) * 8 + i;
        int r = c * 4 + (lane >> 4);         // kv row 0..63 (256B rows)
        int sb = (lane & 15) ^ (r & 7);
        ssrc[i] = kg + (size_t)(h * 4096 + sg * 2048 + r) * 128 + sb * 8;
        sdst[i] = sg * 32768 + c * 1024;
      }
    } else {         // V stager: tile [128][64] u16
      sstep = 64;
#pragma unroll
      for (int i = 0; i < 8; ++i) {
        int c = (w & 1) * 8 + i;
        int r = c * 8 + (lane >> 3);         // d row 0..127 (128B rows)
        int sb = (lane & 7) ^ (r & 7);
        ssrc[i] = vtg + (size_t)(h * 128 + r) * 4096 + sg * 2048 + sb * 8;
        sdst[i] = 65536 + sg * 32768 + c * 1024;
      }
    }
  }

  // Q fragments, B-operand: lane holds col q = qc*32+ql; slice s covers d=s*16+hl*8+(0..7)
  bf16x8 qf[2][8];
#pragma unroll
  for (int qc = 0; qc < 2; ++qc) {
    const u16* qrow =
        qg + (size_t)(h * 4096 + qb * 256 + qw * 64 + qc * 32 + ql) * 128 + hl * 8;
#pragma unroll
    for (int s = 0; s < 8; ++s) qf[qc][s] = *(const bf16x8*)(qrow + s * 16);
  }

  f32x16 of[2][4];
#pragma unroll
  for (int qc = 0; qc < 2; ++qc)
#pragma unroll
    for (int i = 0; i < 4; ++i)
#pragma unroll
      for (int r = 0; r < 16; ++r) of[qc][i][r] = 0.f;
  float mrun[2] = {-1e30f, -1e30f}, lsum[2] = {0.f, 0.f};
  const float sc2 = 0.08838834764831845f * 1.4426950408889634f;
  const float thr = 6.0f / sc2;  // defer-max: P bounded by 2^6

  // prologue: stage tile 0 into buffer 0
#pragma unroll
  for (int i = 0; i < 8; ++i) gload16(ssrc[i], smb + sdst[i]);

  for (int t = 0; t < 32; ++t) {
    const int cur = t & 1;
    asm volatile("s_waitcnt vmcnt(0)" ::: "memory");
    __builtin_amdgcn_s_barrier();
    asm volatile("" ::: "memory");
    if (t + 1 < 32) {
      const int nb = (t + 1) & 1;
#pragma unroll
      for (int i = 0; i < 8; ++i)
        gload16(ssrc[i] + (size_t)(t + 1) * sstep, smb + sdst[i] + nb * 16384);
    }
    const char* kbuf = smb + g2 * 32768 + cur * 16384;
    const char* vbuf = smb + 65536 + g2 * 32768 + cur * 16384;

    // S^T = K * Q^T: each K read feeds 4 MFMAs (2 qc share k-fragment)
    f32x16 st[2][2];
#pragma unroll
    for (int qc = 0; qc < 2; ++qc)
#pragma unroll
      for (int kb = 0; kb < 2; ++kb)
#pragma unroll
        for (int r = 0; r < 16; ++r) st[qc][kb][r] = 0.f;
    const int swz = (ql & 7) << 4;
#pragma unroll
    for (int s = 0; s < 8; ++s) {
      int off = (s * 32 + hl * 16) ^ swz;
      bf16x8 k0 = *(const bf16x8*)(kbuf + ql * 256 + off);
      bf16x8 k1 = *(const bf16x8*)(kbuf + (32 + ql) * 256 + off);
      st[0][0] = MFMA32(k0, qf[0][s], st[0][0]);
      st[0][1] = MFMA32(k1, qf[0][s], st[0][1]);
      st[1][0] = MFMA32(k0, qf[1][s], st[1][0]);
      st[1][1] = MFMA32(k1, qf[1][s], st[1][1]);
    }

    // online softmax per qc (q lane-local; lane^32 holds complementary kv)
    union U { unsigned u[4]; bf16x8 v; };
    U paf[2][4];
#pragma unroll
    for (int qc = 0; qc < 2; ++qc) {
      float tmax = -1e30f;
#pragma unroll
      for (int r = 0; r < 16; ++r)
        tmax = fmaxf(tmax, fmaxf(st[qc][0][r], st[qc][1][r]));
      tmax = fmaxf(tmax, __shfl_xor(tmax, 32));
      float esc;
      float mnew;
      if (__all(tmax - mrun[qc] <= thr)) {  // defer-max: skip rescale
        mnew = mrun[qc];
        esc = 1.f;
      } else {
        mnew = fmaxf(mrun[qc], tmax);
        esc = EXP2((mrun[qc] - mnew) * sc2);
#pragma unroll
        for (int db = 0; db < 4; ++db)
#pragma unroll
          for (int r = 0; r < 16; ++r) of[qc][db][r] *= esc;
        mrun[qc] = mnew;
      }
      float mb = mnew * sc2;
      float psum = 0.f;
      unsigned pk0[8], pk1[8];
#pragma unroll
      for (int i = 0; i < 8; ++i) {
        float a0 = EXP2(st[qc][0][2 * i] * sc2 - mb);
        float b0 = EXP2(st[qc][0][2 * i + 1] * sc2 - mb);
        float a1 = EXP2(st[qc][1][2 * i] * sc2 - mb);
        float b1 = EXP2(st[qc][1][2 * i + 1] * sc2 - mb);
        psum += (a0 + b0) + (a1 + b1);
        pk0[i] = cvtpk(a0, b0);
        pk1[i] = cvtpk(a1, b1);
      }
      psum += __shfl_xor(psum, 32);
      lsum[qc] = lsum[qc] * esc + psum;

      pl32swap(pk0[0], pk0[2]); pl32swap(pk0[1], pk0[3]);
      pl32swap(pk0[4], pk0[6]); pl32swap(pk0[5], pk0[7]);
      pl32swap(pk1[0], pk1[2]); pl32swap(pk1[1], pk1[3]);
      pl32swap(pk1[4], pk1[6]); pl32swap(pk1[5], pk1[7]);
#pragma unroll
      for (int i = 0; i < 4; ++i) {
        paf[qc][0].u[i] = pk0[i];
        paf[qc][1].u[i] = pk0[4 + i];
        paf[qc][2].u[i] = pk1[i];
        paf[qc][3].u[i] = pk1[4 + i];
      }
    }

    // O^T += Vt * P^T: each V read feeds 2 MFMAs
#pragma unroll
    for (int db = 0; db < 4; ++db) {
      int rr = db * 32 + ql;
      int vswz = (rr & 7) << 4;
#pragma unroll
      for (int kp = 0; kp < 4; ++kp) {
        bf16x8 vf = *(const bf16x8*)(vbuf + rr * 128 + ((kp * 32 + hl * 16) ^ vswz));
        of[0][db] = MFMA32(vf, paf[0][kp].v, of[0][db]);
        of[1][db] = MFMA32(vf, paf[1][kp].v, of[1][db]);
      }
    }
    asm volatile("" ::: "memory");
  }

  // ---- split-KV merge: waves 4-7 publish (O',m,l); waves 0-3 combine & store
  __syncthreads();
  if (w >= 4) {
    char* base = smb + qw * 33792 + lane * 512;
#pragma unroll
    for (int qc = 0; qc < 2; ++qc)
#pragma unroll
      for (int db = 0; db < 4; ++db)
        *(f32x16*)(base + (qc * 4 + db) * 64) = of[qc][db];
    float4 ml;
    ml.x = mrun[0]; ml.y = lsum[0]; ml.z = mrun[1]; ml.w = lsum[1];
    *(float4*)(smb + qw * 33792 + 32768 + lane * 16) = ml;
  }
  __syncthreads();
  if (w < 4) {
    const char* base = smb + qw * 33792 + lane * 512;
    float4 ml = *(const float4*)(smb + qw * 33792 + 32768 + lane * 16);
#pragma unroll
    for (int qc = 0; qc < 2; ++qc) {
      float mo = (qc == 0) ? ml.x : ml.z;
      float lo = (qc == 0) ? ml.y : ml.w;
      float m = fmaxf(mrun[qc], mo);
      float aa = EXP2((mrun[qc] - m) * sc2);
      float ab = EXP2((mo - m) * sc2);
      float l = lsum[qc] * aa + lo * ab;
      float linv = 1.f / (l + 1e-8f);
      float faa = aa * linv, fab = ab * linv;
      size_t qrow_o = (size_t)(qb * 256 + qw * 64 + qc * 32 + ql) * 2048 + h * 128;
#pragma unroll
      for (int db = 0; db < 4; ++db) {
        f32x16 ob = *(const f32x16*)(base + (qc * 4 + db) * 64);
#pragma unroll
        for (int u = 0; u < 4; ++u) {
          ushort4 pk;
          pk.x = f2bf(of[qc][db][4 * u + 0] * faa + ob[4 * u + 0] * fab);
          pk.y = f2bf(of[qc][db][4 * u + 1] * faa + ob[4 * u + 1] * fab);
          pk.z = f2bf(of[qc][db][4 * u + 2] * faa + ob[4 * u + 2] * fab);
          pk.w = f2bf(of[qc][db][4 * u + 3] * faa + ob[4 * u + 3] * fab);
          *(ushort4*)(og + qrow_o + db * 32 + 8 * u + hl * 4) = pk;
        }
      }
    }
  }
}

// ---------------------------------------------------------------- launcher
extern "C" void kernel_launch(void* const* d_in, const int* in_sizes, int n_in,
                              void* d_out, int out_size, void* d_ws, size_t ws_size,
                              hipStream_t stream) {
  const float* x = (const float*)d_in[0];      // [4096][2048]
  const float* w_qkv = (const float*)d_in[1];  // [6144][2048]
  const float* w_out = (const float*)d_in[2];  // [2048][2048]

  char* ws = (char*)d_ws;
  u16* xb = (u16*)(ws + 0);            // 16 MB
  u16* wqkvb = (u16*)(ws + 16777216);  // 24 MB
  u16* woutb = (u16*)(ws + 41943040);  // 8 MB
  u16* qb = (u16*)(ws + 50331648);     // 16 MB  [NH][S][HD]
  u16* kb = (u16*)(ws + 67108864);     // 16 MB  [NH][S][HD]
  u16* vtb = (u16*)(ws + 83886080);    // 16 MB  [NH][HD][S]
  u16* aob = (u16*)(ws + 100663296);   // 16 MB  [S][H]

  cast_bf16<<<8192, 256, 0, stream>>>(x, xb, 2097152);
  cast_bf16<<<12288, 256, 0, stream>>>(w_qkv, wqkvb, 3145728);
  cast_bf16<<<4096, 256, 0, stream>>>(w_out, woutb, 1048576);

  gemm_bt<0><<<32 * 48, 256, 0, stream>>>(xb, wqkvb, qb, kb, vtb, 4096, 6144, 2048, 32);
  attn_kernel<<<256, 512, 0, stream>>>(qb, kb, vtb, aob);
  gemm_bt<1><<<32 * 16, 256, 0, stream>>>(aob, woutb, d_out, nullptr, nullptr, 4096, 2048, 2048, 32);
}

// Round 8
// 360.469 us; speedup vs baseline: 1.3931x; 1.3931x over previous
//
#include <hip/hip_runtime.h>
#include <stdint.h>

typedef __attribute__((ext_vector_type(4))) float f32x4;
typedef __attribute__((ext_vector_type(16))) float f32x16;
typedef __attribute__((ext_vector_type(8))) short bf16x8;
typedef unsigned short u16;

#define MFMA(a, b, c) __builtin_amdgcn_mfma_f32_16x16x32_bf16(a, b, c, 0, 0, 0)
#define MFMA32(a, b, c) __builtin_amdgcn_mfma_f32_32x32x16_bf16(a, b, c, 0, 0, 0)
#define EXP2(x) __builtin_amdgcn_exp2f(x)

__device__ __forceinline__ u16 f2bf(float f) {
  union { float f; unsigned u; } x; x.f = f;
  unsigned r = x.u + 0x7fffu + ((x.u >> 16) & 1u);
  return (u16)(r >> 16);
}

__device__ __forceinline__ unsigned cvtpk(float lo, float hi) {
  unsigned r;
  asm("v_cvt_pk_bf16_f32 %0, %1, %2" : "=v"(r) : "v"(lo), "v"(hi));
  return r;
}

// swap: a[32..63] <-> b[0..31]
__device__ __forceinline__ void pl32swap(unsigned& a, unsigned& b) {
  asm volatile("v_permlane32_swap_b32 %0, %1" : "+v"(a), "+v"(b));
}

__device__ __forceinline__ void gload16(const void* g, void* l) {
  __builtin_amdgcn_global_load_lds(
      (const __attribute__((address_space(1))) unsigned int*)g,
      (__attribute__((address_space(3))) unsigned int*)l, 16, 0, 0);
}

// ---------------------------------------------------------------- cast f32->bf16
__global__ void __launch_bounds__(256) cast_bf16(const float* __restrict__ in,
                                                 u16* __restrict__ out, int n4) {
  int i = blockIdx.x * 256 + threadIdx.x;
  if (i >= n4) return;
  float4 v = reinterpret_cast<const float4*>(in)[i];
  ushort4 o;
  o.x = f2bf(v.x); o.y = f2bf(v.y); o.z = f2bf(v.z); o.w = f2bf(v.w);
  reinterpret_cast<ushort4*>(out)[i] = o;
}

// ---------------------------------------------------------------- GEMM C = A * B^T
// XCD-chunked block remap (T1): each XCD owns a contiguous slice of (nb-major)
// tile space -> B-panels stay L2-resident per XCD, A streams from L3.
template <int EPI>
__global__ void __launch_bounds__(256, 2)
gemm_bt(const u16* __restrict__ A, const u16* __restrict__ B,
        void* __restrict__ C0, void* __restrict__ C1, void* __restrict__ C2,
        int M, int N, int K, int MB) {
  __shared__ alignas(16) u16 sm[8192];  // A tile [128][32] @0, B tile [128][32] @4096
  const int tid = threadIdx.x;
  const int w = tid >> 6, lane = tid & 63;
  const int lr = lane & 15, g = lane >> 4;
  const int gb = (blockIdx.x & 7) * ((int)gridDim.x >> 3) + (blockIdx.x >> 3);
  const int mb = gb % MB, nb = gb / MB;
  const int m0 = mb * 128, n0 = nb * 128;

  const u16* src[4];
  u16* dst[4];
#pragma unroll
  for (int i = 0; i < 4; ++i) {
    int c = w * 4 + i;
    int r = (c & 7) * 16 + (lane >> 2);
    int sb = (lane & 3) ^ ((r >> 1) & 3);
    src[i] = (c < 8) ? (A + (size_t)(m0 + r) * K + sb * 8)
                     : (B + (size_t)(n0 + r) * K + sb * 8);
    dst[i] = &sm[c * 512];
  }

  f32x4 acc[4][4];
#pragma unroll
  for (int x = 0; x < 4; ++x)
#pragma unroll
    for (int y = 0; y < 4; ++y) acc[x][y] = f32x4{0.f, 0.f, 0.f, 0.f};

  const int rowb = (w >> 1) * 64, colb = (w & 1) * 64;
  const int nk = K >> 5;
  for (int kt = 0; kt < nk; ++kt) {
#pragma unroll
    for (int i = 0; i < 4; ++i) gload16(src[i] + kt * 32, dst[i]);
    __syncthreads();
    bf16x8 af[4], bfr[4];
#pragma unroll
    for (int mi = 0; mi < 4; ++mi) {
      int r = rowb + mi * 16 + lr;
      af[mi] = *(const bf16x8*)((const char*)sm + r * 64 +
                                ((g * 16) ^ (((r >> 1) & 3) << 4)));
    }
#pragma unroll
    for (int ni = 0; ni < 4; ++ni) {
      int r = colb + ni * 16 + lr;
      bfr[ni] = *(const bf16x8*)((const char*)sm + 8192 + r * 64 +
                                 ((g * 16) ^ (((r >> 1) & 3) << 4)));
    }
#pragma unroll
    for (int mi = 0; mi < 4; ++mi)
#pragma unroll
      for (int ni = 0; ni < 4; ++ni)
        acc[mi][ni] = MFMA(af[mi], bfr[ni], acc[mi][ni]);
    __syncthreads();
  }

  // epilogue: C/D layout col = lr, row = g*4 + j (per m89/m91)
  if (EPI == 0) {
    u16* qo = (u16*)C0;
    u16* ko = (u16*)C1;
    u16* vo = (u16*)C2;
#pragma unroll
    for (int mi = 0; mi < 4; ++mi) {
      int s0 = m0 + rowb + mi * 16 + g * 4;
#pragma unroll
      for (int ni = 0; ni < 4; ++ni) {
        int n = n0 + colb + ni * 16 + lr;
        int t = n >> 11, hh = (n >> 7) & 15, d = n & 127;
        if (t == 2) {  // v transposed: [NH][HD][S], 4 consecutive s per lane
          ushort4 pk;
          pk.x = f2bf(acc[mi][ni][0]);
          pk.y = f2bf(acc[mi][ni][1]);
          pk.z = f2bf(acc[mi][ni][2]);
          pk.w = f2bf(acc[mi][ni][3]);
          *(ushort4*)(vo + (size_t)(hh * 128 + d) * 4096 + s0) = pk;
        } else {
          u16* dq = (t == 0 ? qo : ko) + (size_t)(hh * 4096 + s0) * 128 + d;
#pragma unroll
          for (int j = 0; j < 4; ++j) dq[(size_t)j * 128] = f2bf(acc[mi][ni][j]);
        }
      }
    }
  } else {
    float* C = (float*)C0;
#pragma unroll
    for (int mi = 0; mi < 4; ++mi)
#pragma unroll
      for (int ni = 0; ni < 4; ++ni) {
        size_t r0 = (size_t)(m0 + rowb + mi * 16 + g * 4);
        int cn = n0 + colb + ni * 16 + lr;
#pragma unroll
        for (int j = 0; j < 4; ++j) C[(r0 + j) * N + cn] = acc[mi][ni][j];
      }
  }
}

// ---------------------------------------------------------------- flash attention
// R4 structure (182us): 32x32x16 MFMA, in-register P, O^T accumulate, q=32/wave,
// 4 waves, dbuf K/V, 512 blocks (2/CU). Added: XCD swizzle (L2-resident K/V),
// defer-max (T13), setprio around MFMA clusters (T5).
__global__ void __launch_bounds__(256, 2)
attn_kernel(const u16* __restrict__ qg, const u16* __restrict__ kg,
            const u16* __restrict__ vtg, u16* __restrict__ og) {
  __shared__ alignas(16) u16 sm[32768];
  const int tid = threadIdx.x;
  const int w = tid >> 6, lane = tid & 63;
  const int ql = lane & 31, hl = lane >> 5;
  const int gb = (blockIdx.x & 7) * 64 + (blockIdx.x >> 3);  // XCD swizzle (512=8*64)
  const int h = gb >> 5;
  const int qb = gb & 31;

  // staging: waves 0,1 -> K tile (16 chunks), waves 2,3 -> Vt tile (16 chunks)
  const u16* ssrc[8];
  u16* sdst[8];  // buffer-0 dests; buffer 1 = +8192 u16
  size_t sstep;
  if (w < 2) {
    sstep = 64 * 128;
#pragma unroll
    for (int i = 0; i < 8; ++i) {
      int c = (w & 1) * 8 + i;
      int r = c * 4 + (lane >> 4);           // kv row 0..63 (256B rows)
      int sb = (lane & 15) ^ (r & 7);
      ssrc[i] = kg + (size_t)(h * 4096 + r) * 128 + sb * 8;
      sdst[i] = &sm[c * 512];
    }
  } else {
    sstep = 64;
#pragma unroll
    for (int i = 0; i < 8; ++i) {
      int c = (w & 1) * 8 + i;
      int r = c * 8 + (lane >> 3);           // d row 0..127 (128B rows)
      int sb = (lane & 7) ^ (r & 7);
      ssrc[i] = vtg + (size_t)(h * 128 + r) * 4096 + sb * 8;
      sdst[i] = &sm[16384 + c * 512];
    }
  }

  // Q fragments, B-operand of 32x32x16: lane holds col q=ql, d-slice s = hl*8+(0..7)
  const u16* qrow = qg + (size_t)(h * 4096 + qb * 128 + w * 32 + ql) * 128 + hl * 8;
  bf16x8 qf[8];
#pragma unroll
  for (int s = 0; s < 8; ++s) qf[s] = *(const bf16x8*)(qrow + s * 16);

  f32x16 of[4];
#pragma unroll
  for (int i = 0; i < 4; ++i)
#pragma unroll
    for (int r = 0; r < 16; ++r) of[i][r] = 0.f;
  float mrun = -1e30f, lsum = 0.f;
  const float sc2 = 0.08838834764831845f * 1.4426950408889634f;
  const float thr = 6.0f / sc2;  // defer-max: P bounded by 2^6

  // prologue: stage tile 0 into buffer 0
#pragma unroll
  for (int i = 0; i < 8; ++i) gload16(ssrc[i], sdst[i]);

  for (int t = 0; t < 64; ++t) {
    const int cur = t & 1;
    asm volatile("s_waitcnt vmcnt(0)" ::: "memory");
    __builtin_amdgcn_s_barrier();
    asm volatile("" ::: "memory");
    if (t + 1 < 64) {
      const int nb = (t + 1) & 1;
#pragma unroll
      for (int i = 0; i < 8; ++i)
        gload16(ssrc[i] + (size_t)(t + 1) * sstep, sdst[i] + nb * 8192);
    }
    const char* kbuf = (const char*)sm + cur * 16384;
    const char* vbuf = (const char*)sm + 32768 + cur * 16384;

    // S^T = K * Q^T: lane owns q-col ql; rows = k
    f32x16 st0, st1;
#pragma unroll
    for (int r = 0; r < 16; ++r) { st0[r] = 0.f; st1[r] = 0.f; }
    const int swz = (ql & 7) << 4;
    __builtin_amdgcn_s_setprio(1);
#pragma unroll
    for (int s = 0; s < 8; ++s) {
      int off = (s * 32 + hl * 16) ^ swz;
      bf16x8 k0 = *(const bf16x8*)(kbuf + ql * 256 + off);
      bf16x8 k1 = *(const bf16x8*)(kbuf + (32 + ql) * 256 + off);
      st0 = MFMA32(k0, qf[s], st0);
      st1 = MFMA32(k1, qf[s], st1);
    }
    __builtin_amdgcn_s_setprio(0);

    // online softmax, q = ql lane-local; lane^32 holds complementary k's
    float tmax = -1e30f;
#pragma unroll
    for (int r = 0; r < 16; ++r) tmax = fmaxf(tmax, fmaxf(st0[r], st1[r]));
    tmax = fmaxf(tmax, __shfl_xor(tmax, 32));
    if (!__all(tmax - mrun <= thr)) {  // defer-max: rescale only on real growth
      float mnew = fmaxf(mrun, tmax);
      float esc = EXP2((mrun - mnew) * sc2);
#pragma unroll
      for (int db = 0; db < 4; ++db)
#pragma unroll
        for (int r = 0; r < 16; ++r) of[db][r] *= esc;
      lsum *= esc;
      mrun = mnew;
    }
    float mb2 = mrun * sc2;
    float psum = 0.f;
    unsigned pk0[8], pk1[8];
#pragma unroll
    for (int i = 0; i < 8; ++i) {
      float a0 = EXP2(st0[2 * i] * sc2 - mb2);
      float b0 = EXP2(st0[2 * i + 1] * sc2 - mb2);
      float a1 = EXP2(st1[2 * i] * sc2 - mb2);
      float b1 = EXP2(st1[2 * i + 1] * sc2 - mb2);
      psum += (a0 + b0) + (a1 + b1);
      pk0[i] = cvtpk(a0, b0);
      pk1[i] = cvtpk(a1, b1);
    }
    psum += __shfl_xor(psum, 32);
    lsum += psum;

    // P^T B-fragments in-register: swap halves so lane gets its 8 contiguous k's
    pl32swap(pk0[0], pk0[2]); pl32swap(pk0[1], pk0[3]);
    pl32swap(pk0[4], pk0[6]); pl32swap(pk0[5], pk0[7]);
    pl32swap(pk1[0], pk1[2]); pl32swap(pk1[1], pk1[3]);
    pl32swap(pk1[4], pk1[6]); pl32swap(pk1[5], pk1[7]);
    union U { unsigned u[4]; bf16x8 v; };
    U paf[4];
#pragma unroll
    for (int i = 0; i < 4; ++i) { paf[0].u[i] = pk0[i]; paf[1].u[i] = pk0[4 + i]; }
#pragma unroll
    for (int i = 0; i < 4; ++i) { paf[2].u[i] = pk1[i]; paf[3].u[i] = pk1[4 + i]; }

    // O^T += Vt * P^T
    __builtin_amdgcn_s_setprio(1);
#pragma unroll
    for (int db = 0; db < 4; ++db) {
      int rr = db * 32 + ql;
      int vswz = (rr & 7) << 4;
#pragma unroll
      for (int kp = 0; kp < 4; ++kp) {
        bf16x8 vf = *(const bf16x8*)(vbuf + rr * 128 + ((kp * 32 + hl * 16) ^ vswz));
        of[db] = MFMA32(vf, paf[kp].v, of[db]);
      }
    }
    __builtin_amdgcn_s_setprio(0);
    asm volatile("" ::: "memory");
  }

  // epilogue: lane owns q = ql; d = db*32 + (r&3) + 8*(r>>2) + 4*hl
  float linv = 1.f / (lsum + 1e-8f);
  size_t qrow_o = (size_t)(qb * 128 + w * 32 + ql) * 2048 + h * 128;
#pragma unroll
  for (int db = 0; db < 4; ++db)
#pragma unroll
    for (int u = 0; u < 4; ++u) {
      ushort4 pk;
      pk.x = f2bf(of[db][4 * u + 0] * linv);
      pk.y = f2bf(of[db][4 * u + 1] * linv);
      pk.z = f2bf(of[db][4 * u + 2] * linv);
      pk.w = f2bf(of[db][4 * u + 3] * linv);
      *(ushort4*)(og + qrow_o + db * 32 + 8 * u + hl * 4) = pk;
    }
}

// ---------------------------------------------------------------- launcher
extern "C" void kernel_launch(void* const* d_in, const int* in_sizes, int n_in,
                              void* d_out, int out_size, void* d_ws, size_t ws_size,
                              hipStream_t stream) {
  const float* x = (const float*)d_in[0];      // [4096][2048]
  const float* w_qkv = (const float*)d_in[1];  // [6144][2048]
  const float* w_out = (const float*)d_in[2];  // [2048][2048]

  char* ws = (char*)d_ws;
  u16* xb = (u16*)(ws + 0);            // 16 MB
  u16* wqkvb = (u16*)(ws + 16777216);  // 24 MB
  u16* woutb = (u16*)(ws + 41943040);  // 8 MB
  u16* qb = (u16*)(ws + 50331648);     // 16 MB  [NH][S][HD]
  u16* kb = (u16*)(ws + 67108864);     // 16 MB  [NH][S][HD]
  u16* vtb = (u16*)(ws + 83886080);    // 16 MB  [NH][HD][S]
  u16* aob = (u16*)(ws + 100663296);   // 16 MB  [S][H]

  cast_bf16<<<8192, 256, 0, stream>>>(x, xb, 2097152);
  cast_bf16<<<12288, 256, 0, stream>>>(w_qkv, wqkvb, 3145728);
  cast_bf16<<<4096, 256, 0, stream>>>(w_out, woutb, 1048576);

  gemm_bt<0><<<32 * 48, 256, 0, stream>>>(xb, wqkvb, qb, kb, vtb, 4096, 6144, 2048, 32);
  attn_kernel<<<512, 256, 0, stream>>>(qb, kb, vtb, aob);
  gemm_bt<1><<<32 * 16, 256, 0, stream>>>(aob, woutb, d_out, nullptr, nullptr, 4096, 2048, 2048, 32);
}